// Round 9
// baseline (73.548 us; speedup 1.0000x reference)
//
#include <hip/hip_runtime.h>
#include <hip/hip_bf16.h>

// B=8, T=2048, E=1024, H=64
// Round 9: proj re-shaped for TLP: M=32/block, 512 blocks x 256 thr, ring-2
// 32KB tiles (64KB LDS) -> 2 blocks/CU (2 waves/SIMD). Fragment-major
// global_load_lds staging kept (x staged f32, cvt at read; W pre-transposed
// bf16). Plain 2-phase step: {syncthreads; stage(I+1); compute(I)} -- the
// drain covers loads issued a full step earlier; the co-resident 2nd block
// hides the rest. attn/reduce/wprep unchanged from round 8.
//
// Workspace: qb 2MB | kvb 4MB | partial 16MB | Wtb 384KB

typedef __attribute__((ext_vector_type(4))) float f32x4;
typedef __attribute__((ext_vector_type(4))) float float4_t;
typedef __attribute__((ext_vector_type(8))) short short8;
typedef __attribute__((ext_vector_type(4))) unsigned uint4_t;
typedef __attribute__((ext_vector_type(2))) unsigned uint2_t;

#define MFMA32(a, b, c) __builtin_amdgcn_mfma_f32_16x16x32_bf16(a, b, c, 0, 0, 0)

__device__ __forceinline__ short f2bf(float f) {
  unsigned u = __builtin_bit_cast(unsigned, f);
  unsigned r = (u + 0x7FFFu + ((u >> 16) & 1u)) >> 16;  // RNE
  return (short)r;
}

__device__ __forceinline__ unsigned cvt_pk_bf16(float lo, float hi) {
  unsigned r;
  asm volatile("v_cvt_pk_bf16_f32 %0, %1, %2" : "=v"(r) : "v"(lo), "v"(hi));
  return r;  // low16=bf16(lo), high16=bf16(hi)
}

__device__ __forceinline__ void gload16(const short* g, short* l) {
  __builtin_amdgcn_global_load_lds(
      (const __attribute__((address_space(1))) unsigned*)g,
      (__attribute__((address_space(3))) unsigned*)l, 16, 0, 0);
}

// ---------------- Kernel 0: W transpose+convert ----------------
// Wtb[n_global][k] bf16, n_global = wi*64 + n in [0,192), k in [0,1024)
__global__ __launch_bounds__(256) void wprep_kernel(
    const float* __restrict__ Wq, const float* __restrict__ Wk,
    const float* __restrict__ Wv, short* __restrict__ Wtb) {
  int lin = blockIdx.x * 256 + threadIdx.x;  // 24576 threads
  int n = lin & 63;
  int k8 = (lin >> 6) & 127;
  int wi = lin >> 13;
  const float* W = (wi == 0) ? Wq : (wi == 1) ? Wk : Wv;
  short* dst = Wtb + wi * 65536 + n * 1024 + k8 * 8;
#pragma unroll
  for (int i = 0; i < 8; i++) dst[i] = f2bf(W[(k8 * 8 + i) * 64 + n]);
}

// ---------------- Kernel 1: pipelined QKV projection ----------------
// 512 blocks x 256 thr (4 waves). M=32 rows/block, K-tiles of 64, ring-2.
// LDS tile = 32 units x 1KB:
//   u<8  : x units (f32), u = xwr*4 + ks*2 + h; lane l holds
//          x[m0+xwr*16+(l&15)][k0+32ks+8(l>>4)+4h .. +3]
//   u>=8 : W units (bf16), u = 8 + cf*2 + ks (cf=0..11); lane l holds
//          Wtb[cf*16+(l&15)][k0+32ks+8(l>>4) .. +7]
// Wave (wr=w&1, wc=w>>1): 16 rows x 96 cols; both MFMA operands use the
// same k-bijection (k = 32ks+8g+j) -> contraction exact.
__device__ __forceinline__ void proj_stage(const float* __restrict__ x,
                                           const short* __restrict__ Wtb,
                                           short* dst, int m0, int k0, int w, int l) {
  const int g = l >> 4, lr = l & 15;
#pragma unroll
  for (int i = 0; i < 8; i++) {
    int u = w * 8 + i;
    if (u < 8) {
      int xwr = u >> 2, ks = (u >> 1) & 1, h = u & 1;
      const float* src =
          x + (size_t)(m0 + xwr * 16 + lr) * 1024 + k0 + ks * 32 + g * 8 + h * 4;
      gload16((const short*)src, dst + u * 512);
    } else {
      int uu = u - 8, cf = uu >> 1, ks = uu & 1;
      const short* src = Wtb + (cf * 16 + lr) * 1024 + k0 + ks * 32 + g * 8;
      gload16(src, dst + u * 512);
    }
  }
}

__device__ __forceinline__ void proj_compute(const short* __restrict__ ldsb,
                                             f32x4 (&acc)[6], int wr, int wc, int l) {
  short8 a[2];
#pragma unroll
  for (int ks = 0; ks < 2; ks++) {
    f32x4 fa = *(const f32x4*)&ldsb[(wr * 4 + ks * 2 + 0) * 512 + l * 8];
    f32x4 fb = *(const f32x4*)&ldsb[(wr * 4 + ks * 2 + 1) * 512 + l * 8];
    uint4_t u_;
    u_[0] = cvt_pk_bf16(fa[0], fa[1]);
    u_[1] = cvt_pk_bf16(fa[2], fa[3]);
    u_[2] = cvt_pk_bf16(fb[0], fb[1]);
    u_[3] = cvt_pk_bf16(fb[2], fb[3]);
    a[ks] = __builtin_bit_cast(short8, u_);
  }
#pragma unroll
  for (int nf = 0; nf < 6; nf++) {
    int cf = wc * 6 + nf;
#pragma unroll
    for (int ks = 0; ks < 2; ks++) {
      short8 bfrag = *(const short8*)&ldsb[(8 + cf * 2 + ks) * 512 + l * 8];
      acc[nf] = MFMA32(a[ks], bfrag, acc[nf]);
    }
  }
}

__global__ __launch_bounds__(256, 2) void proj_kernel(
    const float* __restrict__ x, const short* __restrict__ Wtb,
    short* __restrict__ qb, short* __restrict__ kvb) {
  __shared__ __align__(16) short lds[2][32 * 512];  // 2 x 32KB
  const int tid = threadIdx.x;
  const int l = tid & 63, w = tid >> 6;
  const int g = l >> 4, lr = l & 15;
  const int wr = w & 1, wc = w >> 1;
  const int m0 = blockIdx.x * 32;

  f32x4 acc[6];
#pragma unroll
  for (int i = 0; i < 6; i++) acc[i] = (f32x4){0.f, 0.f, 0.f, 0.f};

  proj_stage(x, Wtb, &lds[0][0], m0, 0, w, l);

  for (int I = 0; I < 16; I++) {
    __syncthreads();  // drains own stage(I) loads; publishes buf[I&1];
                      // guarantees compute(I-1) done -> buf[(I+1)&1] reusable
    if (I + 1 < 16) proj_stage(x, Wtb, &lds[(I + 1) & 1][0], m0, (I + 1) * 64, w, l);
    proj_compute(&lds[I & 1][0], acc, wr, wc, l);
  }

  // epilogue: verified store formulas (wave = 16 rows x 96 cols)
#pragma unroll
  for (int nf = 0; nf < 6; nf++) {
    int colg0 = wc * 96 + nf * 16;
    int wi = colg0 >> 6;
    int d = (colg0 & 63) + lr;
    // fold 1/sqrt(H)*log2(e) into q so attn softmax uses 2^x directly
    float scale = (wi == 0) ? 0.18033688f : 1.0f;
#pragma unroll
    for (int r = 0; r < 4; r++) {
      int row = m0 + wr * 16 + g * 4 + r;
      int b = row >> 11, t = row & 2047;
      short bv = f2bf(acc[nf][r] * scale);
      if (wi == 0) {
        int idx = (((b * 128 + (t >> 4)) * 2 + (d >> 5)) * 64 +
                   ((((d >> 3) & 3) << 4) | (t & 15))) * 8 + (d & 7);
        qb[idx] = bv;
      } else if (wi == 1) {
        int u = (b << 2) | (((t >> 4) & 1) << 1) | (d >> 5);
        int idx = (((t >> 5) * 64 + u) << 9) +
                  ((((((d >> 3) & 3) << 4)) | (t & 15)) << 3) + (d & 7);
        kvb[idx] = bv;
      } else {
        int u = 32 + (b << 2) + (d >> 4);
        int idx = (((t >> 5) * 64 + u) << 9) +
                  (((((t >> 2) & 3) << 4) | (d & 15)) << 3) + (((t >> 4) & 1) << 2) + (t & 3);
        kvb[idx] = bv;
      }
    }
  }
}

// ---------------- Kernel 2: pipelined fused attention ----------------
__device__ __forceinline__ void stage_step(const short* __restrict__ kvb,
                                           short* lds_buf, int w, int l, int W) {
#pragma unroll
  for (int i = 0; i < 8; i++) {
    int u = w * 8 + i;
    const short* src = kvb + (((size_t)W * 64 + u) << 9) + l * 8;
    gload16(src, lds_buf + u * 512);
  }
}

// 256 blocks x 512 thr = 8 waves: tt = w>>1 (4 t-tiles of 16), dh = w&1.
// Block: 64 t-rows x one 256-s chunk; 8 steps of 32 s. sc = xcd (lin&7).
__global__ __launch_bounds__(512, 2) void attn_kernel(
    const short* __restrict__ qb, const short* __restrict__ kvb,
    short* __restrict__ partial) {
  __shared__ __align__(16) short lds[2][64 * 512];  // 2 x 64KB ring
  const int tid = threadIdx.x;
  const int l = tid & 63, w = tid >> 6;
  const int tt = w >> 1, dh = w & 1;
  const int lin = blockIdx.x;     // 0..255
  const int sc = lin & 7;         // 0..7: per-XCD s-chunk of 256
  const int tblk = lin >> 3;      // 0..31
  const int tb16 = tblk * 4 + tt; // 0..127

  // Q hoisted: 16 x b128
  short8 qf[8][2];
#pragma unroll
  for (int b = 0; b < 8; b++)
#pragma unroll
    for (int ks = 0; ks < 2; ks++)
      qf[b][ks] = *(const short8*)&qb[(size_t)((b * 128 + tb16) * 2 + ks) * 512 + l * 8];

  f32x4 oacc[8][2];
#pragma unroll
  for (int b = 0; b < 8; b++)
#pragma unroll
    for (int n = 0; n < 2; n++) oacc[b][n] = (f32x4){0.f, 0.f, 0.f, 0.f};

  stage_step(kvb, &lds[0][0], w, l, sc * 8);

  for (int it = 0; it < 8; it++) {
    __syncthreads();  // drains step-old staging (free), publishes buf[it]
    if (it + 1 < 8) stage_step(kvb, &lds[(it + 1) & 1][0], w, l, sc * 8 + it + 1);
    const short* ldsc = &lds[it & 1][0];

    uint2_t plo[8], phi[8];
#pragma unroll
    for (int sf = 0; sf < 2; sf++) {
      f32x4 S[8];
      __builtin_amdgcn_s_setprio(1);
#pragma unroll
      for (int b = 0; b < 8; b++) {
        short8 kf0 = *(const short8*)&ldsc[(b * 4 + sf * 2 + 0) * 512 + l * 8];
        short8 kf1 = *(const short8*)&ldsc[(b * 4 + sf * 2 + 1) * 512 + l * 8];
        f32x4 s = (f32x4){0.f, 0.f, 0.f, 0.f};
        s = MFMA32(kf0, qf[b][0], s);
        s = MFMA32(kf1, qf[b][1], s);
        S[b] = s;
      }
      __builtin_amdgcn_s_setprio(0);
      // softmax over batch (elementwise across the 8 register sets)
#pragma unroll
      for (int r = 0; r < 4; r++) {
        float den = 0.f;
#pragma unroll
        for (int b = 0; b < 8; b++) {
          float e = __builtin_amdgcn_exp2f(S[b][r]);
          S[b][r] = e;
          den += e;
        }
        float inv = __builtin_amdgcn_rcpf(den);
#pragma unroll
        for (int b = 0; b < 8; b++) S[b][r] *= inv;
      }
#pragma unroll
      for (int b = 0; b < 8; b++) {
        uint2_t pw;
        pw[0] = cvt_pk_bf16(S[b][0], S[b][1]);
        pw[1] = cvt_pk_bf16(S[b][2], S[b][3]);
        if (sf == 0) plo[b] = pw; else phi[b] = pw;
      }
    }
    // PV k=32: A = V unit (16 d x 32 s, sigma-map), B = packed P
    __builtin_amdgcn_s_setprio(1);
#pragma unroll
    for (int b = 0; b < 8; b++) {
      uint4_t pu;
      pu[0] = plo[b][0]; pu[1] = plo[b][1]; pu[2] = phi[b][0]; pu[3] = phi[b][1];
      short8 pbv = __builtin_bit_cast(short8, pu);
      short8 vf0 = *(const short8*)&ldsc[(32 + b * 4 + dh * 2 + 0) * 512 + l * 8];
      short8 vf1 = *(const short8*)&ldsc[(32 + b * 4 + dh * 2 + 1) * 512 + l * 8];
      oacc[b][0] = MFMA32(vf0, pbv, oacc[b][0]);
      oacc[b][1] = MFMA32(vf1, pbv, oacc[b][1]);
    }
    __builtin_amdgcn_s_setprio(0);
  }

  // store bf16 partial fragment-major (uint2/lane, wave-contiguous 512B runs)
  uint2_t* pout = (uint2_t*)partial;
#pragma unroll
  for (int b = 0; b < 8; b++)
#pragma unroll
    for (int n = 0; n < 2; n++) {
      int df = dh * 2 + n;
      uint2_t pk;
      pk[0] = cvt_pk_bf16(oacc[b][n][0], oacc[b][n][1]);
      pk[1] = cvt_pk_bf16(oacc[b][n][2], oacc[b][n][3]);
      __builtin_nontemporal_store(
          pk, &pout[(size_t)(((sc * 8 + b) * 128 + tb16) * 4 + df) * 64 + l]);
    }
}

// ---------------- Kernel 3: reduce bf16 partials -> f32 out ----------------
__global__ __launch_bounds__(256) void reduce_kernel(const short* __restrict__ partial,
                                                     float* __restrict__ out) {
  int i = blockIdx.x * 256 + threadIdx.x;  // 0..262143: (b,tb16,df,l)
  const uint2_t* p = (const uint2_t*)partial;
  float4_t a = (float4_t){0.f, 0.f, 0.f, 0.f};
  for (int sc = 0; sc < 8; sc++) {
    uint2_t v = __builtin_nontemporal_load(&p[(size_t)sc * 262144 + i]);
    a[0] += __builtin_bit_cast(float, v[0] << 16);
    a[1] += __builtin_bit_cast(float, v[0] & 0xFFFF0000u);
    a[2] += __builtin_bit_cast(float, v[1] << 16);
    a[3] += __builtin_bit_cast(float, v[1] & 0xFFFF0000u);
  }
  int b = i >> 15;
  int r1 = i & 32767;
  int tb16 = r1 >> 8;
  int r2 = r1 & 255;
  int df = r2 >> 6;
  int ll = r2 & 63;
  int gg = ll >> 4, lrr = ll & 15;
  *(float4_t*)&out[(size_t)(b * 2048 + tb16 * 16 + lrr) * 64 + df * 16 + gg * 4] = a;
}

extern "C" void kernel_launch(void* const* d_in, const int* in_sizes, int n_in,
                              void* d_out, int out_size, void* d_ws, size_t ws_size,
                              hipStream_t stream) {
  const float* x = (const float*)d_in[0];
  const float* Wq = (const float*)d_in[1];
  const float* Wk = (const float*)d_in[2];
  const float* Wv = (const float*)d_in[3];
  float* out = (float*)d_out;

  char* ws = (char*)d_ws;
  short* qb = (short*)ws;                     // 2MB
  short* kvb = qb + 16384 * 64;               // 4MB (64 windows x 64 units)
  short* partial = kvb + 2 * 16384 * 64;      // 16MB bf16 fragment-major
  short* Wtb = partial + 8ull * 262144 * 4;   // 384KB

  wprep_kernel<<<96, 256, 0, stream>>>(Wq, Wk, Wv, Wtb);
  proj_kernel<<<512, 256, 0, stream>>>(x, Wtb, qb, kvb);
  attn_kernel<<<256, 512, 0, stream>>>(qb, kvb, partial);
  reduce_kernel<<<1024, 256, 0, stream>>>(partial, out);
}

// Round 10
// 62.969 us; speedup vs baseline: 1.1680x; 1.1680x over previous
//
#include <hip/hip_runtime.h>
#include <hip/hip_bf16.h>

// B=8, T=2048, E=1024, H=64
// Round 10: proj = M=64/block (256 blocks) x 512 thr (8 waves), K-tile=32,
// ring-3 of 20KB tiles (60KB LDS): 2 waves/SIMD TLP *and* 2-tile-deep
// counted-vmcnt prefetch (vmcnt(5), never 0 mid-loop), 1 barrier/step.
// Waves 0-3 stage 5 units each; waves 4-7 stage none (their vmcnt(5) is
// trivially satisfied - vmcnt is per-wave). Lesson from r9: timed-graph
// performance needs pipeline DEPTH (r8) not just block TLP (r9) -- this has
// both. attn/reduce/wprep unchanged from r8/r9 (verified).
//
// Workspace: qb 2MB | kvb 4MB | partial 16MB | Wtb 384KB

typedef __attribute__((ext_vector_type(4))) float f32x4;
typedef __attribute__((ext_vector_type(4))) float float4_t;
typedef __attribute__((ext_vector_type(8))) short short8;
typedef __attribute__((ext_vector_type(4))) unsigned uint4_t;
typedef __attribute__((ext_vector_type(2))) unsigned uint2_t;

#define MFMA32(a, b, c) __builtin_amdgcn_mfma_f32_16x16x32_bf16(a, b, c, 0, 0, 0)

__device__ __forceinline__ short f2bf(float f) {
  unsigned u = __builtin_bit_cast(unsigned, f);
  unsigned r = (u + 0x7FFFu + ((u >> 16) & 1u)) >> 16;  // RNE
  return (short)r;
}

__device__ __forceinline__ unsigned cvt_pk_bf16(float lo, float hi) {
  unsigned r;
  asm volatile("v_cvt_pk_bf16_f32 %0, %1, %2" : "=v"(r) : "v"(lo), "v"(hi));
  return r;  // low16=bf16(lo), high16=bf16(hi)
}

__device__ __forceinline__ void gload16(const short* g, short* l) {
  __builtin_amdgcn_global_load_lds(
      (const __attribute__((address_space(1))) unsigned*)g,
      (__attribute__((address_space(3))) unsigned*)l, 16, 0, 0);
}

// ---------------- Kernel 0: W transpose+convert ----------------
// Wtb[n_global][k] bf16, n_global = wi*64 + n in [0,192), k in [0,1024)
__global__ __launch_bounds__(256) void wprep_kernel(
    const float* __restrict__ Wq, const float* __restrict__ Wk,
    const float* __restrict__ Wv, short* __restrict__ Wtb) {
  int lin = blockIdx.x * 256 + threadIdx.x;  // 24576 threads
  int n = lin & 63;
  int k8 = (lin >> 6) & 127;
  int wi = lin >> 13;
  const float* W = (wi == 0) ? Wq : (wi == 1) ? Wk : Wv;
  short* dst = Wtb + wi * 65536 + n * 1024 + k8 * 8;
#pragma unroll
  for (int i = 0; i < 8; i++) dst[i] = f2bf(W[(k8 * 8 + i) * 64 + n]);
}

// ---------------- Kernel 1: pipelined QKV projection ----------------
// LDS tile = 20 units x 1KB (K-tile = 32):
//   u<8  : x units (f32), u = xwr*2 + h; lane l holds
//          x[m0+xwr*16+(l&15)][k0 + 8*(l>>4) + 4h .. +3]
//   u>=8 : W units (bf16), u = 8 + cf (cf=0..11); lane l holds
//          Wtb[cf*16+(l&15)][k0 + 8*(l>>4) .. +7]
// Wave (wr=w&3, wc=w>>2): 16 rows x 96 cols, acc[6]. Both operands use the
// same k-bijection k = 8g + j -> contraction exact.
__device__ __forceinline__ void proj_stage(const float* __restrict__ x,
                                           const short* __restrict__ Wtb,
                                           short* dst, int m0, int k0, int w, int l) {
  const int g = l >> 4, lr = l & 15;
  if (w < 4) {
#pragma unroll
    for (int i = 0; i < 5; i++) {
      int u = w * 5 + i;
      if (u < 8) {
        int xwr = u >> 1, h = u & 1;
        const float* src = x + (size_t)(m0 + xwr * 16 + lr) * 1024 + k0 + g * 8 + h * 4;
        gload16((const short*)src, dst + u * 512);
      } else {
        int cf = u - 8;
        const short* src = Wtb + (cf * 16 + lr) * 1024 + k0 + g * 8;
        gload16(src, dst + u * 512);
      }
    }
  }
}

__device__ __forceinline__ void proj_compute(const short* __restrict__ ldsb,
                                             f32x4 (&acc)[6], int wr, int wc, int l) {
  f32x4 fa = *(const f32x4*)&ldsb[(wr * 2 + 0) * 512 + l * 8];  // k slots 0..3
  f32x4 fb = *(const f32x4*)&ldsb[(wr * 2 + 1) * 512 + l * 8];  // k slots 4..7
  uint4_t u_;
  u_[0] = cvt_pk_bf16(fa[0], fa[1]);
  u_[1] = cvt_pk_bf16(fa[2], fa[3]);
  u_[2] = cvt_pk_bf16(fb[0], fb[1]);
  u_[3] = cvt_pk_bf16(fb[2], fb[3]);
  short8 a = __builtin_bit_cast(short8, u_);
#pragma unroll
  for (int nf = 0; nf < 6; nf++) {
    int cf = wc * 6 + nf;
    short8 bfrag = *(const short8*)&ldsb[(8 + cf) * 512 + l * 8];
    acc[nf] = MFMA32(a, bfrag, acc[nf]);
  }
}

__global__ __launch_bounds__(512) void proj_kernel(
    const float* __restrict__ x, const short* __restrict__ Wtb,
    short* __restrict__ qb, short* __restrict__ kvb) {
  __shared__ __align__(16) short lds[3 * 20 * 512];  // 60KB ring-3
  const int tid = threadIdx.x;
  const int l = tid & 63, w = tid >> 6;
  const int g = l >> 4, lr = l & 15;
  const int wr = w & 3, wc = w >> 2;
  const int m0 = blockIdx.x * 64;

  f32x4 acc[6];
#pragma unroll
  for (int i = 0; i < 6; i++) acc[i] = (f32x4){0.f, 0.f, 0.f, 0.f};

  short* bA = lds;
  short* bB = lds + 10240;
  short* bC = lds + 20480;
  proj_stage(x, Wtb, bA, m0, 0, w, l);
  proj_stage(x, Wtb, bB, m0, 32, w, l);

  for (int I = 0; I < 31; I++) {
    // outstanding/wave (w<4): rem(tile I) + 5(tile I+1) -> vmcnt(5) = tile I
    // landed; waves 4-7 have 0 outstanding and pass immediately.
    asm volatile("s_waitcnt vmcnt(5)" ::: "memory");
    __builtin_amdgcn_s_barrier();
    __builtin_amdgcn_sched_barrier(0);
    if (I + 2 < 32) proj_stage(x, Wtb, bC, m0, (I + 2) * 32, w, l);
    proj_compute(bA, acc, wr, wc, l);
    short* t = bA; bA = bB; bB = bC; bC = t;
  }
  asm volatile("s_waitcnt vmcnt(0)" ::: "memory");
  __builtin_amdgcn_s_barrier();
  __builtin_amdgcn_sched_barrier(0);
  proj_compute(bA, acc, wr, wc, l);

  // epilogue: verified store formulas (wave = 16 rows x 96 cols)
#pragma unroll
  for (int nf = 0; nf < 6; nf++) {
    int colg0 = wc * 96 + nf * 16;
    int wi = colg0 >> 6;
    int d = (colg0 & 63) + lr;
    // fold 1/sqrt(H)*log2(e) into q so attn softmax uses 2^x directly
    float scale = (wi == 0) ? 0.18033688f : 1.0f;
#pragma unroll
    for (int r = 0; r < 4; r++) {
      int row = m0 + wr * 16 + g * 4 + r;
      int b = row >> 11, t = row & 2047;
      short bv = f2bf(acc[nf][r] * scale);
      if (wi == 0) {
        int idx = (((b * 128 + (t >> 4)) * 2 + (d >> 5)) * 64 +
                   ((((d >> 3) & 3) << 4) | (t & 15))) * 8 + (d & 7);
        qb[idx] = bv;
      } else if (wi == 1) {
        int u = (b << 2) | (((t >> 4) & 1) << 1) | (d >> 5);
        int idx = (((t >> 5) * 64 + u) << 9) +
                  ((((((d >> 3) & 3) << 4)) | (t & 15)) << 3) + (d & 7);
        kvb[idx] = bv;
      } else {
        int u = 32 + (b << 2) + (d >> 4);
        int idx = (((t >> 5) * 64 + u) << 9) +
                  (((((t >> 2) & 3) << 4) | (d & 15)) << 3) + (((t >> 4) & 1) << 2) + (t & 3);
        kvb[idx] = bv;
      }
    }
  }
}

// ---------------- Kernel 2: pipelined fused attention ----------------
__device__ __forceinline__ void stage_step(const short* __restrict__ kvb,
                                           short* lds_buf, int w, int l, int W) {
#pragma unroll
  for (int i = 0; i < 8; i++) {
    int u = w * 8 + i;
    const short* src = kvb + (((size_t)W * 64 + u) << 9) + l * 8;
    gload16(src, lds_buf + u * 512);
  }
}

// 256 blocks x 512 thr = 8 waves: tt = w>>1 (4 t-tiles of 16), dh = w&1.
// Block: 64 t-rows x one 256-s chunk; 8 steps of 32 s. sc = xcd (lin&7).
__global__ __launch_bounds__(512, 2) void attn_kernel(
    const short* __restrict__ qb, const short* __restrict__ kvb,
    short* __restrict__ partial) {
  __shared__ __align__(16) short lds[2][64 * 512];  // 2 x 64KB ring
  const int tid = threadIdx.x;
  const int l = tid & 63, w = tid >> 6;
  const int tt = w >> 1, dh = w & 1;
  const int lin = blockIdx.x;     // 0..255
  const int sc = lin & 7;         // 0..7: per-XCD s-chunk of 256
  const int tblk = lin >> 3;      // 0..31
  const int tb16 = tblk * 4 + tt; // 0..127

  // Q hoisted: 16 x b128
  short8 qf[8][2];
#pragma unroll
  for (int b = 0; b < 8; b++)
#pragma unroll
    for (int ks = 0; ks < 2; ks++)
      qf[b][ks] = *(const short8*)&qb[(size_t)((b * 128 + tb16) * 2 + ks) * 512 + l * 8];

  f32x4 oacc[8][2];
#pragma unroll
  for (int b = 0; b < 8; b++)
#pragma unroll
    for (int n = 0; n < 2; n++) oacc[b][n] = (f32x4){0.f, 0.f, 0.f, 0.f};

  stage_step(kvb, &lds[0][0], w, l, sc * 8);

  for (int it = 0; it < 8; it++) {
    __syncthreads();  // drains step-old staging (free), publishes buf[it]
    if (it + 1 < 8) stage_step(kvb, &lds[(it + 1) & 1][0], w, l, sc * 8 + it + 1);
    const short* ldsc = &lds[it & 1][0];

    uint2_t plo[8], phi[8];
#pragma unroll
    for (int sf = 0; sf < 2; sf++) {
      f32x4 S[8];
      __builtin_amdgcn_s_setprio(1);
#pragma unroll
      for (int b = 0; b < 8; b++) {
        short8 kf0 = *(const short8*)&ldsc[(b * 4 + sf * 2 + 0) * 512 + l * 8];
        short8 kf1 = *(const short8*)&ldsc[(b * 4 + sf * 2 + 1) * 512 + l * 8];
        f32x4 s = (f32x4){0.f, 0.f, 0.f, 0.f};
        s = MFMA32(kf0, qf[b][0], s);
        s = MFMA32(kf1, qf[b][1], s);
        S[b] = s;
      }
      __builtin_amdgcn_s_setprio(0);
      // softmax over batch (elementwise across the 8 register sets)
#pragma unroll
      for (int r = 0; r < 4; r++) {
        float den = 0.f;
#pragma unroll
        for (int b = 0; b < 8; b++) {
          float e = __builtin_amdgcn_exp2f(S[b][r]);
          S[b][r] = e;
          den += e;
        }
        float inv = __builtin_amdgcn_rcpf(den);
#pragma unroll
        for (int b = 0; b < 8; b++) S[b][r] *= inv;
      }
#pragma unroll
      for (int b = 0; b < 8; b++) {
        uint2_t pw;
        pw[0] = cvt_pk_bf16(S[b][0], S[b][1]);
        pw[1] = cvt_pk_bf16(S[b][2], S[b][3]);
        if (sf == 0) plo[b] = pw; else phi[b] = pw;
      }
    }
    // PV k=32: A = V unit (16 d x 32 s, sigma-map), B = packed P
    __builtin_amdgcn_s_setprio(1);
#pragma unroll
    for (int b = 0; b < 8; b++) {
      uint4_t pu;
      pu[0] = plo[b][0]; pu[1] = plo[b][1]; pu[2] = phi[b][0]; pu[3] = phi[b][1];
      short8 pbv = __builtin_bit_cast(short8, pu);
      short8 vf0 = *(const short8*)&ldsc[(32 + b * 4 + dh * 2 + 0) * 512 + l * 8];
      short8 vf1 = *(const short8*)&ldsc[(32 + b * 4 + dh * 2 + 1) * 512 + l * 8];
      oacc[b][0] = MFMA32(vf0, pbv, oacc[b][0]);
      oacc[b][1] = MFMA32(vf1, pbv, oacc[b][1]);
    }
    __builtin_amdgcn_s_setprio(0);
  }

  // store bf16 partial fragment-major (uint2/lane, wave-contiguous 512B runs)
  uint2_t* pout = (uint2_t*)partial;
#pragma unroll
  for (int b = 0; b < 8; b++)
#pragma unroll
    for (int n = 0; n < 2; n++) {
      int df = dh * 2 + n;
      uint2_t pk;
      pk[0] = cvt_pk_bf16(oacc[b][n][0], oacc[b][n][1]);
      pk[1] = cvt_pk_bf16(oacc[b][n][2], oacc[b][n][3]);
      __builtin_nontemporal_store(
          pk, &pout[(size_t)(((sc * 8 + b) * 128 + tb16) * 4 + df) * 64 + l]);
    }
}

// ---------------- Kernel 3: reduce bf16 partials -> f32 out ----------------
__global__ __launch_bounds__(256) void reduce_kernel(const short* __restrict__ partial,
                                                     float* __restrict__ out) {
  int i = blockIdx.x * 256 + threadIdx.x;  // 0..262143: (b,tb16,df,l)
  const uint2_t* p = (const uint2_t*)partial;
  float4_t a = (float4_t){0.f, 0.f, 0.f, 0.f};
  for (int sc = 0; sc < 8; sc++) {
    uint2_t v = __builtin_nontemporal_load(&p[(size_t)sc * 262144 + i]);
    a[0] += __builtin_bit_cast(float, v[0] << 16);
    a[1] += __builtin_bit_cast(float, v[0] & 0xFFFF0000u);
    a[2] += __builtin_bit_cast(float, v[1] << 16);
    a[3] += __builtin_bit_cast(float, v[1] & 0xFFFF0000u);
  }
  int b = i >> 15;
  int r1 = i & 32767;
  int tb16 = r1 >> 8;
  int r2 = r1 & 255;
  int df = r2 >> 6;
  int ll = r2 & 63;
  int gg = ll >> 4, lrr = ll & 15;
  *(float4_t*)&out[(size_t)(b * 2048 + tb16 * 16 + lrr) * 64 + df * 16 + gg * 4] = a;
}

extern "C" void kernel_launch(void* const* d_in, const int* in_sizes, int n_in,
                              void* d_out, int out_size, void* d_ws, size_t ws_size,
                              hipStream_t stream) {
  const float* x = (const float*)d_in[0];
  const float* Wq = (const float*)d_in[1];
  const float* Wk = (const float*)d_in[2];
  const float* Wv = (const float*)d_in[3];
  float* out = (float*)d_out;

  char* ws = (char*)d_ws;
  short* qb = (short*)ws;                     // 2MB
  short* kvb = qb + 16384 * 64;               // 4MB (64 windows x 64 units)
  short* partial = kvb + 2 * 16384 * 64;      // 16MB bf16 fragment-major
  short* Wtb = partial + 8ull * 262144 * 4;   // 384KB

  wprep_kernel<<<96, 256, 0, stream>>>(Wq, Wk, Wv, Wtb);
  proj_kernel<<<256, 512, 0, stream>>>(x, Wtb, qb, kvb);
  attn_kernel<<<256, 512, 0, stream>>>(qb, kvb, partial);
  reduce_kernel<<<1024, 256, 0, stream>>>(partial, out);
}